// Round 5
// baseline (121573.010 us; speedup 1.0000x reference)
//
#include <hip/hip_runtime.h>
#include <math.h>

#define V 13000
#define D 300
#define M 500
#define B 64
#define NW 5
#define T 128
#define NSUP (B*NW)       // 320
#define NSEQ (NSUP + B)   // 384
#define CT 64             // chains per tile (= lanes per wave)
#define NCT 6             // 384/64
#define MB 12             // m per compute block (3 per wave x 4 waves)
#define NMB 42            // ceil(500/12)
#define NSLICE (2*NMB)    // 84 (dir, mb) weight panels
#define SPX 11            // ceil(84/8) slices per XCD
#define NCOMP (8*SPX*NCT) // 528 compute blocks (some idle)
#define NGATH (2*NSEQ)    // 768 gather blocks
#define AROW 800          // act row: k<300 = x, k>=300 = c

__device__ __forceinline__ float sigmoidf_(float x){ return 1.0f/(1.0f+expf(-x)); }

// actT layout: actT[(dir*NSEQ + rank)*AROW + k]

__global__ void init_kernel(const float* __restrict__ c0L, const float* __restrict__ c0R,
                            float* __restrict__ actT0, float* __restrict__ c_final)
{
    int idx = blockIdx.x*256 + threadIdx.x;      // 2*384*500
    if (idx >= 2*NSEQ*M) return;
    int dir = idx / (NSEQ*M);
    int rem = idx % (NSEQ*M);
    int a = rem / NSEQ;                          // m 0..499
    int r = rem % NSEQ;                          // rank / chain
    float v = dir ? c0R[a] : c0L[a];
    c_final[((size_t)dir*NSEQ + r)*M + a] = v;
    actT0[((size_t)dir*NSEQ + r)*AROW + 300 + a] = v;
}

__global__ void sort_kernel(const int* __restrict__ blank_sup, const int* __restrict__ blank_tgt,
                            int* __restrict__ perm, int* __restrict__ lenR, int* __restrict__ tmax)
{
    __shared__ int L0[NSEQ], L1[NSEQ];
    int tid = threadIdx.x;                       // 384 threads
    int blank = (tid < NSUP) ? blank_sup[tid] : blank_tgt[tid - NSUP];
    int l0 = blank, l1 = (T-1) - blank;
    L0[tid] = l0; L1[tid] = l1;
    __syncthreads();
    int r0 = 0, r1 = 0;
    for (int j = 0; j < NSEQ; ++j) {
        int c = L0[j]; r0 += (c > l0) || (c == l0 && j < tid);
        int d = L1[j]; r1 += (d > l1) || (d == l1 && j < tid);
    }
    perm[r0] = tid;        lenR[r0] = l0;
    perm[NSEQ + r1] = tid; lenR[NSEQ + r1] = l1;
    __syncthreads();
    if (tid < 2*NCT) {
        int dir = tid / NCT, t = tid % NCT;
        tmax[tid] = lenR[dir*NSEQ + t*CT];       // descending -> first rank in tile is max
    }
}

// fused-multiply chunk: NF4 float4 of acts held in registers across all 9 weight rows
template<int NF4>
__device__ __forceinline__ void chunk_fma(const float4* __restrict__ ap,
                                          const float* const wr[3][3], int kofs,
                                          float acc[3][3])
{
    float4 a[NF4];
    #pragma unroll
    for (int q = 0; q < NF4; ++q) a[q] = ap[q];
    #pragma unroll
    for (int j = 0; j < 3; ++j) {
        #pragma unroll
        for (int g = 0; g < 3; ++g) {
            const float4* wp = (const float4*)(wr[j][g] + kofs);
            float s0 = 0.f, s1 = 0.f, s2 = 0.f, s3 = 0.f;
            #pragma unroll
            for (int q = 0; q < NF4; ++q) {
                float4 w = wp[q];
                s0 += w.x * a[q].x;
                s1 += w.y * a[q].y;
                s2 += w.z * a[q].z;
                s3 += w.w * a[q].w;
            }
            acc[j][g] += (s0 + s1) + (s2 + s3);
        }
    }
}

// -------- per-step fused kernel: compute blocks (step s) + gather blocks (x for s+1) ----
__global__ __launch_bounds__(256, 2)
void step_fused(int s,
                const float* __restrict__ actT_cur, float* __restrict__ actT_next,
                float* __restrict__ c_final,
                const float* __restrict__ WL, const float* __restrict__ UL, const float* __restrict__ bL,
                const float* __restrict__ WR, const float* __restrict__ UR, const float* __restrict__ bR,
                const int* __restrict__ perm, const int* __restrict__ lenR, const int* __restrict__ tmax,
                const int* __restrict__ sup_tok, const int* __restrict__ tgt_tok,
                const float* __restrict__ emb)
{
    const int bid = blockIdx.x;
    if (bid < NCOMP) {
        if (s < 0) return;
        // XCD co-location: 6 ct-blocks of one slice share bid%8 and are dispatch-adjacent
        const int x  = bid & 7;
        const int jj = bid >> 3;                 // 0..65
        const int ct = jj % NCT;
        const int sl = jj / NCT;                 // 0..10
        const int slice = sl*8 + x;              // 0..87
        if (slice >= NSLICE) return;
        const int dir = slice / NMB;
        const int mb  = slice % NMB;
        if (s >= tmax[dir*NCT + ct]) return;     // whole chain-tile finished

        const int wave  = threadIdx.x >> 6;      // 0..3
        const int lane  = threadIdx.x & 63;
        const int rank  = ct*CT + lane;
        const int len   = lenR[dir*NSEQ + rank];
        const int chain = perm[dir*NSEQ + rank];
        const int m0    = mb*MB + wave*3;        // this wave's 3 m rows

        const float* Wd = dir ? WR : WL;
        const float* Ud = dir ? UR : UL;
        const float* bias = dir ? bR : bL;

        int mm[3];
        #pragma unroll
        for (int j = 0; j < 3; ++j) {
            int m = m0 + j; if (m >= M) m = M-1;          // clamp; garbage rows discarded at write
            mm[j] = __builtin_amdgcn_readfirstlane(m);
        }

        float acc[3][3];
        #pragma unroll
        for (int j = 0; j < 3; ++j)
            #pragma unroll
            for (int g = 0; g < 3; ++g)
                acc[j][g] = bias[g*M + mm[j]];

        const float* arow = actT_cur + ((size_t)dir*NSEQ + rank)*AROW;
        const float4* arow4 = (const float4*)arow;

        // ---- W phase: K = 0..300 over x ----
        {
            const float* wr[3][3];
            #pragma unroll
            for (int j = 0; j < 3; ++j)
                #pragma unroll
                for (int g = 0; g < 3; ++g)
                    wr[j][g] = Wd + (size_t)(g*M + mm[j])*D;
            chunk_fma<20>(arow4 +  0, wr,   0, acc);
            chunk_fma<20>(arow4 + 20, wr,  80, acc);
            chunk_fma<20>(arow4 + 40, wr, 160, acc);
            chunk_fma<15>(arow4 + 60, wr, 240, acc);
        }
        // ---- U phase: K = 0..500 over c (act offset 300) ----
        {
            const float* wr[3][3];
            #pragma unroll
            for (int j = 0; j < 3; ++j)
                #pragma unroll
                for (int g = 0; g < 3; ++g)
                    wr[j][g] = Ud + (size_t)(g*M + mm[j])*M;
            chunk_fma<20>(arow4 +  75, wr,   0, acc);
            chunk_fma<20>(arow4 +  95, wr,  80, acc);
            chunk_fma<20>(arow4 + 115, wr, 160, acc);
            chunk_fma<20>(arow4 + 135, wr, 240, acc);
            chunk_fma<20>(arow4 + 155, wr, 320, acc);
            chunk_fma<20>(arow4 + 175, wr, 400, acc);
            chunk_fma< 5>(arow4 + 195, wr, 480, acc);
        }

        // ---- cell update into next step's actT; snapshot at s==len-1 ----
        float* anext = actT_next + ((size_t)dir*NSEQ + rank)*AROW;
        #pragma unroll
        for (int j = 0; j < 3; ++j) {
            const int m = m0 + j;
            if (m >= M) continue;                 // wave-uniform
            float cold = arow[300 + m];
            float f  = sigmoidf_(acc[j][0]);
            float i2 = sigmoidf_(acc[j][1]);
            float cb = tanhf(acc[j][2]);
            float cn = (s < len) ? (f*cold + i2*cb) : cold;
            anext[300 + m] = cn;
            if (s == len - 1) c_final[((size_t)dir*NSEQ + chain)*M + m] = cn;
        }
    } else {
        // gather x-part for step s+1 into actT_next
        const int gb = bid - NCOMP;              // 0..767
        const int dir = gb / NSEQ;
        const int rank = gb % NSEQ;
        const int sn = s + 1;
        if (sn >= T-1) return;
        if (sn >= tmax[dir*NCT + rank/CT]) return;
        const int ch = perm[dir*NSEQ + rank];
        const int tpos = dir ? (T-1 - sn) : sn;
        const int tok = (ch < NSUP) ? sup_tok[ch*T + tpos] : tgt_tok[(ch - NSUP)*T + tpos];
        const float* src = emb + (size_t)tok*D;
        float* dst = actT_next + ((size_t)dir*NSEQ + rank)*AROW;
        for (int k = threadIdx.x; k < D; k += 256) dst[k] = src[k];
    }
}

__global__ void env_kernel(const float* __restrict__ l_states, const float* __restrict__ r_states,
                           const float* __restrict__ Wo, const float* __restrict__ Uo,
                           const float* __restrict__ bo,
                           float* __restrict__ env)
{
    __shared__ __align__(16) float l[M];
    __shared__ __align__(16) float r[M];
    const int i = blockIdx.x;
    const int tid = threadIdx.x;
    for (int m=tid; m<M; m+=blockDim.x){ l[m]=l_states[i*M+m]; r[m]=r_states[i*M+m]; }
    __syncthreads();
    for (int d=tid; d<D; d+=blockDim.x) {
        const float4* wo = reinterpret_cast<const float4*>(Wo + (size_t)d*M);
        const float4* uo = reinterpret_cast<const float4*>(Uo + (size_t)d*M);
        const float4* lv = reinterpret_cast<const float4*>(l);
        const float4* rv = reinterpret_cast<const float4*>(r);
        float acc = bo[d];
        #pragma unroll 5
        for (int q=0; q<M/4; ++q) {
            float4 a=wo[q], bv=lv[q], u=uo[q], rr=rv[q];
            acc += a.x*bv.x + a.y*bv.y + a.z*bv.z + a.w*bv.w;
            acc += u.x*rr.x + u.y*rr.y + u.z*rr.z + u.w*rr.w;
        }
        env[i*D + d] = tanhf(acc);
    }
}

__global__ void episode_kernel(const float* __restrict__ env, const int* __restrict__ target_y,
                               float* __restrict__ flags, float* __restrict__ losses)
{
    const int b = blockIdx.x;
    const int lane = threadIdx.x;
    const float* tgt = env + (size_t)(NSUP + b)*D;

    float tn = 0.f;
    for (int d=lane; d<D; d+=64){ float v=tgt[d]; tn += v*v; }
    for (int off=32; off; off>>=1) tn += __shfl_down(tn, off);
    tn = __shfl(tn, 0);

    float z[NW];
    for (int n=0; n<NW; ++n){
        const float* sup = env + (size_t)(b*NW + n)*D;
        float dot=0.f, sn=0.f;
        for (int d=lane; d<D; d+=64){ float sv=sup[d], tv=tgt[d]; dot+=sv*tv; sn+=sv*sv; }
        for (int off=32; off; off>>=1){ dot += __shfl_down(dot,off); sn += __shfl_down(sn,off); }
        dot = __shfl(dot,0); sn = __shfl(sn,0);
        float denom = fmaxf(sqrtf(sn)*sqrtf(tn), 1e-8f);
        z[n] = dot/denom*10.0f;
    }

    if (lane==0){
        float mx=z[0];
        for(int n=1;n<NW;n++) mx=fmaxf(mx,z[n]);
        float se=0.f; float p[NW];
        for(int n=0;n<NW;n++){ p[n]=expf(z[n]-mx); se+=p[n]; }
        for(int n=0;n<NW;n++) p[n]/=se;
        int am=0; float bv=p[0];
        for(int n=1;n<NW;n++) if(p[n]>bv){bv=p[n];am=n;}
        int y = target_y[b];
        flags[b] = (am==y)?1.0f:0.0f;
        float mx2=p[0]; for(int n=1;n<NW;n++) mx2=fmaxf(mx2,p[n]);
        float se2=0.f; for(int n=0;n<NW;n++) se2+=expf(p[n]-mx2);
        losses[b] = -(p[y]-mx2-logf(se2));
    }
}

__global__ void finalize_kernel(const float* __restrict__ flags, const float* __restrict__ losses,
                                float* __restrict__ out)
{
    const int lane = threadIdx.x; // 64 threads
    float f = flags[lane], l = losses[lane];
    for (int off=32; off; off>>=1){ f += __shfl_down(f,off); l += __shfl_down(l,off); }
    if (lane==0){ out[0] = f/(float)B; out[1] = l/(float)B; }
}

extern "C" void kernel_launch(void* const* d_in, const int* in_sizes, int n_in,
                              void* d_out, int out_size, void* d_ws, size_t ws_size,
                              hipStream_t stream) {
    const int*   sup_tok   = (const int*)d_in[0];
    const int*   tgt_tok   = (const int*)d_in[1];
    const int*   blank_sup = (const int*)d_in[2];
    const int*   blank_tgt = (const int*)d_in[3];
    const int*   target_y  = (const int*)d_in[4];
    const float* emb = (const float*)d_in[5];
    const float* WL  = (const float*)d_in[6];
    const float* UL  = (const float*)d_in[7];
    const float* bL  = (const float*)d_in[8];
    const float* WR  = (const float*)d_in[9];
    const float* UR  = (const float*)d_in[10];
    const float* bR  = (const float*)d_in[11];
    const float* Wo  = (const float*)d_in[12];
    const float* Uo  = (const float*)d_in[13];
    const float* bo  = (const float*)d_in[14];
    const float* c0L = (const float*)d_in[15];
    const float* c0R = (const float*)d_in[16];

    const size_t ACTSZ = (size_t)2*NSEQ*AROW;      // 614400 floats per buffer
    float* ws_f = (float*)d_ws;
    float* actT0   = ws_f;
    float* actT1   = actT0 + ACTSZ;
    float* c_final = actT1 + ACTSZ;                // [2*384*500]
    float* env     = c_final + 2*NSEQ*M;           // [384*300]
    float* flags   = env + NSEQ*D;                 // [64]
    float* losses  = flags + B;                    // [64]
    int*   perm    = (int*)(losses + B);           // [2*384]
    int*   lenR    = perm + 2*NSEQ;                // [2*384]
    int*   tmax    = lenR + 2*NSEQ;                // [12]

    init_kernel<<<(2*NSEQ*M + 255)/256, 256, 0, stream>>>(c0L, c0R, actT0, c_final);
    sort_kernel<<<1, NSEQ, 0, stream>>>(blank_sup, blank_tgt, perm, lenR, tmax);

    // prologue: gather x for step 0 into actT0 (compute blocks no-op at s=-1)
    step_fused<<<NCOMP + NGATH, 256, 0, stream>>>(-1, actT1, actT0, c_final,
                                                  WL, UL, bL, WR, UR, bR,
                                                  perm, lenR, tmax, sup_tok, tgt_tok, emb);
    for (int s = 0; s < T-1; ++s) {
        float* cur  = (s & 1) ? actT1 : actT0;
        float* next = (s & 1) ? actT0 : actT1;
        step_fused<<<NCOMP + NGATH, 256, 0, stream>>>(s, cur, next, c_final,
                                                      WL, UL, bL, WR, UR, bR,
                                                      perm, lenR, tmax, sup_tok, tgt_tok, emb);
    }

    env_kernel<<<NSEQ, 256, 0, stream>>>(c_final, c_final + NSEQ*M, Wo, Uo, bo, env);
    episode_kernel<<<B, 64, 0, stream>>>(env, target_y, flags, losses);
    finalize_kernel<<<1, 64, 0, stream>>>(flags, losses, (float*)d_out);
}

// Round 6
// 7855.934 us; speedup vs baseline: 15.4753x; 15.4753x over previous
//
#include <hip/hip_runtime.h>
#include <math.h>

#define V 13000
#define D 300
#define M 500
#define B 64
#define NW 5
#define T 128
#define NSUP (B*NW)        // 320
#define NSEQ (NSUP + B)    // 384
#define CT 64
#define NCT 6
#define GSTRIDE 512        // row = g*512 + m (pad m 500..511)
#define RPAD 1536
#define NRT 24             // row tiles of 64 (each tile within one gate)
#define KTOT 800
#define KC 20              // k per chunk
#define NCHUNK 40
#define XCHUNKS 15         // chunks 0..14 are x (k<300), rest are c
#define KS 2               // K split
#define CPK 20             // chunks per split
#define NGB (2*KS*NCT*NRT) // 576 gemm blocks

__device__ __forceinline__ float sigmoidf_(float x){ return 1.0f/(1.0f+expf(-x)); }

// actB layout: actB[(d*M + m)*NSEQ + rank]   (k-major, rank minor -> coalesced)
// gpart layout: gpart[((ks*2 + d)*RPAD + row)*NSEQ + rank]

__global__ void init_kernel(const float* __restrict__ c0L, const float* __restrict__ c0R,
                            float* __restrict__ actB0, float* __restrict__ c_final)
{
    int idx = blockIdx.x*256 + threadIdx.x;      // 2*M*NSEQ
    if (idx >= 2*M*NSEQ) return;
    int d = idx / (M*NSEQ);
    int rem = idx % (M*NSEQ);
    int m = rem / NSEQ;
    int r = rem % NSEQ;
    float v = d ? c0R[m] : c0L[m];
    actB0[((size_t)d*M + m)*NSEQ + r] = v;
    c_final[((size_t)d*NSEQ + r)*M + m] = v;
}

__global__ void sort_kernel(const int* __restrict__ blank_sup, const int* __restrict__ blank_tgt,
                            int* __restrict__ perm, int* __restrict__ lenR, int* __restrict__ tmax)
{
    __shared__ int L0[NSEQ], L1[NSEQ];
    int tid = threadIdx.x;                       // 384 threads
    int blank = (tid < NSUP) ? blank_sup[tid] : blank_tgt[tid - NSUP];
    int l0 = blank, l1 = (T-1) - blank;
    L0[tid] = l0; L1[tid] = l1;
    __syncthreads();
    int r0 = 0, r1 = 0;
    for (int j = 0; j < NSEQ; ++j) {
        int c = L0[j]; r0 += (c > l0) || (c == l0 && j < tid);
        int d = L1[j]; r1 += (d > l1) || (d == l1 && j < tid);
    }
    perm[r0] = tid;        lenR[r0] = l0;
    perm[NSEQ + r1] = tid; lenR[NSEQ + r1] = l1;
    __syncthreads();
    if (tid < 2*NCT) {
        int dir = tid / NCT, t = tid % NCT;
        tmax[tid] = lenR[dir*NSEQ + t*CT];       // descending -> first rank in tile is max
    }
}

// ---- per-step GEMM: gpart[ks][d][row][rank] partial over K range ----
__global__ __launch_bounds__(128)
void gemm_step(int s, const float* __restrict__ actB,
               float* __restrict__ gpart,
               const float* __restrict__ WL, const float* __restrict__ UL,
               const float* __restrict__ WR, const float* __restrict__ UR,
               const int* __restrict__ perm, const int* __restrict__ tmax,
               const int* __restrict__ sup_tok, const int* __restrict__ tgt_tok,
               const float* __restrict__ emb)
{
    const int bid = blockIdx.x;                  // ((d*KS+ks)*NCT+ct)*NRT + rt
    const int rt = bid % NRT;
    int tmp = bid / NRT;
    const int ct = tmp % NCT; tmp /= NCT;
    const int ks = tmp % KS;
    const int d  = tmp / KS;
    if (s >= tmax[d*NCT + ct]) return;

    const int tid = threadIdx.x;
    const int tx = tid & 15;                     // chain quad: chains tx*4..+3
    const int ty = tid >> 4;                     // 0..7: rows ty*8..+7
    const int rank0 = ct*CT;

    const float* Wd = d ? WR : WL;
    const float* Ud = d ? UR : UL;

    __shared__ float Asub[KC][68];               // [k][row], padded stride 68 (16B-aligned, bank-shifted)
    __shared__ float Bsub[KC][64];               // [k][chain]
    __shared__ int tok_s[CT];

    if (ks == 0 && tid < CT) {
        int ch = perm[d*NSEQ + rank0 + tid];
        int tpos = d ? (T-1-s) : s;
        tok_s[tid] = (ch < NSUP) ? sup_tok[ch*T + tpos] : tgt_tok[(ch-NSUP)*T + tpos];
    }
    __syncthreads();

    const int gg    = (rt*64) >> 9;              // gate of this row tile
    const int mbase = (rt & 7) * 64;             // m offset of this row tile

    float4 acc[8];
    #pragma unroll
    for (int j = 0; j < 8; ++j) acc[j] = make_float4(0.f,0.f,0.f,0.f);

    const int cbeg = ks*CPK, cend = ks*CPK + CPK;

    // register staging buffers (static-indexed)
    float4 aQ[3];                                // A: 320 f4 -> slots tid, tid+128, tid+256(<320)
    float4 bQ4[3];                               // B c-path: 320 f4
    float  bQx[10];                              // B x-path: 1280 scalars

    // ---- stage loaders (global -> regs) ----
    auto loadA = [&](int chk){
        const int k0 = chk*KC;
        const bool isx = (chk < XCHUNKS);
        #pragma unroll
        for (int sl = 0; sl < 3; ++sl) {
            int i = tid + sl*128;
            if (i < 320) {
                int rl = i/5, kq = i%5;
                int mm = mbase + rl;
                float4 v = make_float4(0.f,0.f,0.f,0.f);
                if (mm < M) {
                    const float* src = isx ? (Wd + ((size_t)(gg*M + mm))*D + (k0 + kq*4))
                                           : (Ud + ((size_t)(gg*M + mm))*M + (k0 - 300 + kq*4));
                    v = *(const float4*)src;
                }
                aQ[sl] = v;
            }
        }
    };
    auto loadB = [&](int chk){
        const int k0 = chk*KC;
        if (chk < XCHUNKS) {
            #pragma unroll
            for (int q = 0; q < 10; ++q) {
                int i = tid + q*128;             // 0..1279
                int kk = i >> 6, c = i & 63;
                bQx[q] = emb[(size_t)tok_s[c]*D + k0 + kk];
            }
        } else {
            #pragma unroll
            for (int sl = 0; sl < 3; ++sl) {
                int i = tid + sl*128;
                if (i < 320) {
                    int kk = i >> 4, c4 = i & 15;
                    bQ4[sl] = *(const float4*)(actB + ((size_t)d*M + (k0-300) + kk)*NSEQ + rank0 + c4*4);
                }
            }
        }
    };
    auto writeAB = [&](int chk){
        #pragma unroll
        for (int sl = 0; sl < 3; ++sl) {
            int i = tid + sl*128;
            if (i < 320) {
                int rl = i/5, kq = i%5;
                float4 v = aQ[sl];
                Asub[kq*4+0][rl] = v.x; Asub[kq*4+1][rl] = v.y;
                Asub[kq*4+2][rl] = v.z; Asub[kq*4+3][rl] = v.w;
            }
        }
        if (chk < XCHUNKS) {
            #pragma unroll
            for (int q = 0; q < 10; ++q) {
                int i = tid + q*128;
                int kk = i >> 6, c = i & 63;
                Bsub[kk][c] = bQx[q];
            }
        } else {
            #pragma unroll
            for (int sl = 0; sl < 3; ++sl) {
                int i = tid + sl*128;
                if (i < 320) {
                    int kk = i >> 4, c4 = i & 15;
                    *(float4*)&Bsub[kk][c4*4] = bQ4[sl];
                }
            }
        }
    };

    loadA(cbeg); loadB(cbeg);
    for (int chk = cbeg; chk < cend; ++chk) {
        writeAB(chk);
        __syncthreads();
        if (chk + 1 < cend) { loadA(chk+1); loadB(chk+1); }
        #pragma unroll
        for (int kk = 0; kk < KC; ++kk) {
            float4 a0 = *(const float4*)&Asub[kk][ty*8];
            float4 a1 = *(const float4*)&Asub[kk][ty*8 + 4];
            float4 b  = *(const float4*)&Bsub[kk][tx*4];
            acc[0].x += a0.x*b.x; acc[0].y += a0.x*b.y; acc[0].z += a0.x*b.z; acc[0].w += a0.x*b.w;
            acc[1].x += a0.y*b.x; acc[1].y += a0.y*b.y; acc[1].z += a0.y*b.z; acc[1].w += a0.y*b.w;
            acc[2].x += a0.z*b.x; acc[2].y += a0.z*b.y; acc[2].z += a0.z*b.z; acc[2].w += a0.z*b.w;
            acc[3].x += a0.w*b.x; acc[3].y += a0.w*b.y; acc[3].z += a0.w*b.z; acc[3].w += a0.w*b.w;
            acc[4].x += a1.x*b.x; acc[4].y += a1.x*b.y; acc[4].z += a1.x*b.z; acc[4].w += a1.x*b.w;
            acc[5].x += a1.y*b.x; acc[5].y += a1.y*b.y; acc[5].z += a1.y*b.z; acc[5].w += a1.y*b.w;
            acc[6].x += a1.z*b.x; acc[6].y += a1.z*b.y; acc[6].z += a1.z*b.z; acc[6].w += a1.z*b.w;
            acc[7].x += a1.w*b.x; acc[7].y += a1.w*b.y; acc[7].z += a1.w*b.z; acc[7].w += a1.w*b.w;
        }
        __syncthreads();
    }

    #pragma unroll
    for (int j = 0; j < 8; ++j) {
        int row = rt*64 + ty*8 + j;
        *(float4*)&gpart[(((size_t)ks*2 + d)*RPAD + row)*NSEQ + rank0 + tx*4] = acc[j];
    }
}

// ---- per-step update: sum K-splits + bias, gate nonlinearities, write c ----
__global__ void update_kernel(int s,
                              const float* __restrict__ actB_cur, float* __restrict__ actB_next,
                              float* __restrict__ c_final, const float* __restrict__ gpart,
                              const float* __restrict__ bL, const float* __restrict__ bR,
                              const int* __restrict__ perm, const int* __restrict__ lenR)
{
    const int bidx = blockIdx.x;                 // 2*M = 1000
    const int d = bidx / M;
    const int m = bidx % M;
    const int rank = threadIdx.x;                // 384
    const float* bias = d ? bR : bL;

    float g[3];
    #pragma unroll
    for (int gg = 0; gg < 3; ++gg) {
        size_t row = (size_t)gg*GSTRIDE + m;
        float v = gpart[((size_t)(0*2 + d)*RPAD + row)*NSEQ + rank]
                + gpart[((size_t)(1*2 + d)*RPAD + row)*NSEQ + rank];
        g[gg] = v + bias[gg*M + m];
    }
    int len = lenR[d*NSEQ + rank];
    float cold = actB_cur[((size_t)d*M + m)*NSEQ + rank];
    float f  = sigmoidf_(g[0]);
    float i2 = sigmoidf_(g[1]);
    float cb = tanhf(g[2]);
    float cn = (s < len) ? (f*cold + i2*cb) : cold;
    actB_next[((size_t)d*M + m)*NSEQ + rank] = cn;
    if (s == len - 1) {
        int ch = perm[d*NSEQ + rank];
        c_final[((size_t)d*NSEQ + ch)*M + m] = cn;
    }
}

__global__ void env_kernel(const float* __restrict__ l_states, const float* __restrict__ r_states,
                           const float* __restrict__ Wo, const float* __restrict__ Uo,
                           const float* __restrict__ bo,
                           float* __restrict__ env)
{
    __shared__ __align__(16) float l[M];
    __shared__ __align__(16) float r[M];
    const int i = blockIdx.x;
    const int tid = threadIdx.x;
    for (int m=tid; m<M; m+=blockDim.x){ l[m]=l_states[i*M+m]; r[m]=r_states[i*M+m]; }
    __syncthreads();
    for (int d=tid; d<D; d+=blockDim.x) {
        const float4* wo = reinterpret_cast<const float4*>(Wo + (size_t)d*M);
        const float4* uo = reinterpret_cast<const float4*>(Uo + (size_t)d*M);
        const float4* lv = reinterpret_cast<const float4*>(l);
        const float4* rv = reinterpret_cast<const float4*>(r);
        float acc = bo[d];
        #pragma unroll 5
        for (int q=0; q<M/4; ++q) {
            float4 a=wo[q], bv=lv[q], u=uo[q], rr=rv[q];
            acc += a.x*bv.x + a.y*bv.y + a.z*bv.z + a.w*bv.w;
            acc += u.x*rr.x + u.y*rr.y + u.z*rr.z + u.w*rr.w;
        }
        env[i*D + d] = tanhf(acc);
    }
}

__global__ void episode_kernel(const float* __restrict__ env, const int* __restrict__ target_y,
                               float* __restrict__ flags, float* __restrict__ losses)
{
    const int b = blockIdx.x;
    const int lane = threadIdx.x;
    const float* tgt = env + (size_t)(NSUP + b)*D;

    float tn = 0.f;
    for (int d=lane; d<D; d+=64){ float v=tgt[d]; tn += v*v; }
    for (int off=32; off; off>>=1) tn += __shfl_down(tn, off);
    tn = __shfl(tn, 0);

    float z[NW];
    for (int n=0; n<NW; ++n){
        const float* sup = env + (size_t)(b*NW + n)*D;
        float dot=0.f, sn=0.f;
        for (int d=lane; d<D; d+=64){ float sv=sup[d], tv=tgt[d]; dot+=sv*tv; sn+=sv*sv; }
        for (int off=32; off; off>>=1){ dot += __shfl_down(dot,off); sn += __shfl_down(sn,off); }
        dot = __shfl(dot,0); sn = __shfl(sn,0);
        float denom = fmaxf(sqrtf(sn)*sqrtf(tn), 1e-8f);
        z[n] = dot/denom*10.0f;
    }

    if (lane==0){
        float mx=z[0];
        for(int n=1;n<NW;n++) mx=fmaxf(mx,z[n]);
        float se=0.f; float p[NW];
        for(int n=0;n<NW;n++){ p[n]=expf(z[n]-mx); se+=p[n]; }
        for(int n=0;n<NW;n++) p[n]/=se;
        int am=0; float bv=p[0];
        for(int n=1;n<NW;n++) if(p[n]>bv){bv=p[n];am=n;}
        int y = target_y[b];
        flags[b] = (am==y)?1.0f:0.0f;
        float mx2=p[0]; for(int n=1;n<NW;n++) mx2=fmaxf(mx2,p[n]);
        float se2=0.f; for(int n=0;n<NW;n++) se2+=expf(p[n]-mx2);
        losses[b] = -(p[y]-mx2-logf(se2));
    }
}

__global__ void finalize_kernel(const float* __restrict__ flags, const float* __restrict__ losses,
                                float* __restrict__ out)
{
    const int lane = threadIdx.x; // 64 threads
    float f = flags[lane], l = losses[lane];
    for (int off=32; off; off>>=1){ f += __shfl_down(f,off); l += __shfl_down(l,off); }
    if (lane==0){ out[0] = f/(float)B; out[1] = l/(float)B; }
}

extern "C" void kernel_launch(void* const* d_in, const int* in_sizes, int n_in,
                              void* d_out, int out_size, void* d_ws, size_t ws_size,
                              hipStream_t stream) {
    const int*   sup_tok   = (const int*)d_in[0];
    const int*   tgt_tok   = (const int*)d_in[1];
    const int*   blank_sup = (const int*)d_in[2];
    const int*   blank_tgt = (const int*)d_in[3];
    const int*   target_y  = (const int*)d_in[4];
    const float* emb = (const float*)d_in[5];
    const float* WL  = (const float*)d_in[6];
    const float* UL  = (const float*)d_in[7];
    const float* bL  = (const float*)d_in[8];
    const float* WR  = (const float*)d_in[9];
    const float* UR  = (const float*)d_in[10];
    const float* bR  = (const float*)d_in[11];
    const float* Wo  = (const float*)d_in[12];
    const float* Uo  = (const float*)d_in[13];
    const float* bo  = (const float*)d_in[14];
    const float* c0L = (const float*)d_in[15];
    const float* c0R = (const float*)d_in[16];

    float* ws_f = (float*)d_ws;
    float* actB0   = ws_f;                              // [2*500*384]
    float* actB1   = actB0 + 2*M*NSEQ;                  // [2*500*384]
    float* gpart   = actB1 + 2*M*NSEQ;                  // [2*2*1536*384] = 9.4 MB
    float* c_final = gpart + (size_t)KS*2*RPAD*NSEQ;    // [2*384*500]
    float* env     = c_final + 2*NSEQ*M;                // [384*300]
    float* flags   = env + NSEQ*D;                      // [64]
    float* losses  = flags + B;                         // [64]
    int*   perm    = (int*)(losses + B);                // [2*384]
    int*   lenR    = perm + 2*NSEQ;                     // [2*384]
    int*   tmax    = lenR + 2*NSEQ;                     // [12]

    init_kernel<<<(2*M*NSEQ + 255)/256, 256, 0, stream>>>(c0L, c0R, actB0, c_final);
    sort_kernel<<<1, NSEQ, 0, stream>>>(blank_sup, blank_tgt, perm, lenR, tmax);

    for (int s = 0; s < T-1; ++s) {
        float* cur  = (s & 1) ? actB1 : actB0;
        float* next = (s & 1) ? actB0 : actB1;
        gemm_step<<<NGB, 128, 0, stream>>>(s, cur, gpart, WL, UL, WR, UR,
                                           perm, tmax, sup_tok, tgt_tok, emb);
        update_kernel<<<2*M, NSEQ, 0, stream>>>(s, cur, next, c_final, gpart,
                                                bL, bR, perm, lenR);
    }

    env_kernel<<<NSEQ, 256, 0, stream>>>(c_final, c_final + NSEQ*M, Wo, Uo, bo, env);
    episode_kernel<<<B, 64, 0, stream>>>(env, target_y, flags, losses);
    finalize_kernel<<<1, 64, 0, stream>>>(flags, losses, (float*)d_out);
}

// Round 7
// 7162.148 us; speedup vs baseline: 16.9744x; 1.0969x over previous
//
#include <hip/hip_runtime.h>
#include <math.h>

#define V 13000
#define D 300
#define M 500
#define B 64
#define NW 5
#define T 128
#define NSUP (B*NW)        // 320
#define NSEQ (NSUP + B)    // 384
#define CT 64              // chains per tile
#define NCT 6
#define MT 16              // m per block
#define NMT 32             // m tiles (covers 512, clamp at 500)
#define NCHUNK 40          // K chunks of 20 (15 x-chunks + 25 c-chunks)
#define XCH 15             // chunks < XCH read x (emb), else c (actB)
#define NSTEP (T-1)        // 127

__device__ __forceinline__ float sigmoidf_(float x){ return 1.0f/(1.0f+expf(-x)); }

// actB layout: actB[(d*M + m)*NSEQ + rank]  (k-major, rank minor -> coalesced)
// c_final layout: c_final[(d*NSEQ + chain)*M + m]

__global__ void init_kernel(const float* __restrict__ c0L, const float* __restrict__ c0R,
                            float* __restrict__ actB0, float* __restrict__ c_final)
{
    int idx = blockIdx.x*256 + threadIdx.x;      // 2*M*NSEQ
    if (idx >= 2*M*NSEQ) return;
    int d = idx / (M*NSEQ);
    int rem = idx % (M*NSEQ);
    int m = rem / NSEQ;
    int r = rem % NSEQ;
    float v = d ? c0R[m] : c0L[m];
    actB0[((size_t)d*M + m)*NSEQ + r] = v;
    c_final[((size_t)d*NSEQ + r)*M + m] = v;
}

__global__ void sort_kernel(const int* __restrict__ blank_sup, const int* __restrict__ blank_tgt,
                            int* __restrict__ perm, int* __restrict__ lenR, int* __restrict__ tmax)
{
    __shared__ int L0[NSEQ], L1[NSEQ];
    int tid = threadIdx.x;                       // 384 threads
    int blank = (tid < NSUP) ? blank_sup[tid] : blank_tgt[tid - NSUP];
    int l0 = blank, l1 = (T-1) - blank;
    L0[tid] = l0; L1[tid] = l1;
    __syncthreads();
    int r0 = 0, r1 = 0;
    for (int j = 0; j < NSEQ; ++j) {
        int c = L0[j]; r0 += (c > l0) || (c == l0 && j < tid);
        int d = L1[j]; r1 += (d > l1) || (d == l1 && j < tid);
    }
    perm[r0] = tid;        lenR[r0] = l0;
    perm[NSEQ + r1] = tid; lenR[NSEQ + r1] = l1;
    __syncthreads();
    if (tid < 2*NCT) {
        int dir = tid / NCT, t = tid % NCT;
        tmax[tid] = lenR[dir*NSEQ + t*CT];       // descending -> first rank in tile is max
    }
}

// -------- fused per-step kernel: GEMM (K=800) + gate nonlinearities + cell update --------
// block = (dir, ct, mtile): 16 m x 3 gates x 64 chains; thread = 1 m x 3 gates x 4 chains.
__global__ __launch_bounds__(256)
void step_kernel(int s,
                 const float* __restrict__ actB_cur, float* __restrict__ actB_next,
                 float* __restrict__ c_final,
                 const float* __restrict__ WL, const float* __restrict__ UL, const float* __restrict__ bL,
                 const float* __restrict__ WR, const float* __restrict__ UR, const float* __restrict__ bR,
                 const int* __restrict__ perm, const int* __restrict__ lenR, const int* __restrict__ tmax,
                 const int* __restrict__ sup_tok, const int* __restrict__ tgt_tok,
                 const float* __restrict__ emb)
{
    // XCD co-location: 6 ct-blocks of one (dir,mtile) group share bid%8
    const int bid = blockIdx.x;                  // 384
    const int x  = bid & 7;
    const int t  = bid >> 3;                     // 0..47
    const int ct = t % NCT;
    const int gs = t / NCT;                      // 0..7
    const int g  = gs*8 + x;                     // 0..63 = (dir, mtile)
    const int d  = g >> 5;
    const int mt = g & 31;
    if (s >= tmax[d*NCT + ct]) return;

    __shared__ float Asub[20][52];               // [k][row 0..47], padded
    __shared__ float Bsub[20][64];               // [k][chain]
    __shared__ int tok_s[CT];
    __shared__ int len_s[CT];

    const int tid = threadIdx.x;
    const int tx = tid & 15;                     // chain quad
    const int ty = tid >> 4;                     // m within tile
    const int rank0 = ct*CT;

    if (tid < CT) {
        int rank = rank0 + tid;
        int ch = perm[d*NSEQ + rank];
        len_s[tid] = lenR[d*NSEQ + rank];
        int tpos = d ? (T-1-s) : s;
        tok_s[tid] = (ch < NSUP) ? sup_tok[ch*T + tpos] : tgt_tok[(ch-NSUP)*T + tpos];
    }
    __syncthreads();

    const float* Wd = d ? WR : WL;
    const float* Ud = d ? UR : UL;
    const float* bias = d ? bR : bL;

    float acc0[4] = {0.f,0.f,0.f,0.f};
    float acc1[4] = {0.f,0.f,0.f,0.f};
    float acc2[4] = {0.f,0.f,0.f,0.f};

    // staging registers
    float4 aReg = make_float4(0.f,0.f,0.f,0.f);
    float  bxReg[5];
    float4 bcReg0 = make_float4(0.f,0.f,0.f,0.f);
    float4 bcReg1 = make_float4(0.f,0.f,0.f,0.f);

    auto loadA = [&](int chk){
        if (tid < 240) {
            int r = tid/5, kq = tid%5;           // r: local row, kq: float4 within 20-k
            int gg = r >> 4, ml = r & 15;
            int m = mt*MT + ml;
            float4 v = make_float4(0.f,0.f,0.f,0.f);
            if (m < M) {
                const float* src = (chk < XCH)
                    ? (Wd + (size_t)(gg*M + m)*D + chk*20 + kq*4)
                    : (Ud + (size_t)(gg*M + m)*M + (chk*20 - 300) + kq*4);
                v = *(const float4*)src;
            }
            aReg = v;
        }
    };
    auto loadB = [&](int chk){
        const int k0 = chk*20;
        if (chk < XCH) {
            #pragma unroll
            for (int q = 0; q < 5; ++q) {
                int i = tid*5 + q;               // 0..1279
                int c = i/20, kk = i%20;
                bxReg[q] = emb[(size_t)tok_s[c]*D + k0 + kk];
            }
        } else {
            {
                int kk = tid >> 4, c4 = tid & 15;
                bcReg0 = *(const float4*)(actB_cur + ((size_t)d*M + (k0-300) + kk)*NSEQ + rank0 + c4*4);
            }
            if (tid < 64) {
                int sl = tid + 256;
                int kk = sl >> 4, c4 = sl & 15;
                bcReg1 = *(const float4*)(actB_cur + ((size_t)d*M + (k0-300) + kk)*NSEQ + rank0 + c4*4);
            }
        }
    };
    auto writeAB = [&](int chk){
        if (tid < 240) {
            int r = tid/5, kq = tid%5;
            Asub[kq*4+0][r] = aReg.x;
            Asub[kq*4+1][r] = aReg.y;
            Asub[kq*4+2][r] = aReg.z;
            Asub[kq*4+3][r] = aReg.w;
        }
        if (chk < XCH) {
            #pragma unroll
            for (int q = 0; q < 5; ++q) {
                int i = tid*5 + q;
                int c = i/20, kk = i%20;
                Bsub[kk][c] = bxReg[q];
            }
        } else {
            {
                int kk = tid >> 4, c4 = tid & 15;
                *(float4*)&Bsub[kk][c4*4] = bcReg0;
            }
            if (tid < 64) {
                int sl = tid + 256;
                int kk = sl >> 4, c4 = sl & 15;
                *(float4*)&Bsub[kk][c4*4] = bcReg1;
            }
        }
    };

    loadA(0); loadB(0);
    for (int chk = 0; chk < NCHUNK; ++chk) {
        writeAB(chk);
        __syncthreads();
        if (chk + 1 < NCHUNK) { loadA(chk+1); loadB(chk+1); }
        #pragma unroll
        for (int kk = 0; kk < 20; ++kk) {
            float a0 = Asub[kk][ty];
            float a1 = Asub[kk][16 + ty];
            float a2 = Asub[kk][32 + ty];
            float4 b = *(const float4*)&Bsub[kk][tx*4];
            acc0[0] += a0*b.x; acc0[1] += a0*b.y; acc0[2] += a0*b.z; acc0[3] += a0*b.w;
            acc1[0] += a1*b.x; acc1[1] += a1*b.y; acc1[2] += a1*b.z; acc1[3] += a1*b.w;
            acc2[0] += a2*b.x; acc2[1] += a2*b.y; acc2[2] += a2*b.z; acc2[3] += a2*b.w;
        }
        __syncthreads();
    }

    // ---- fused cell update (thread-local: all 3 gates for (m, 4 chains)) ----
    const int m = mt*MT + ty;
    if (m < M) {
        const float bf = bias[m], bi = bias[M + m], bc = bias[2*M + m];
        #pragma unroll
        for (int cc = 0; cc < 4; ++cc) {
            int rl   = tx*4 + cc;
            int rank = rank0 + rl;
            int len  = len_s[rl];
            size_t cidx = ((size_t)d*M + m)*NSEQ + rank;
            float cold = actB_cur[cidx];
            float f  = sigmoidf_(acc0[cc] + bf);
            float i2 = sigmoidf_(acc1[cc] + bi);
            float cb = tanhf(acc2[cc] + bc);
            float cn = (s < len) ? (f*cold + i2*cb) : cold;
            actB_next[cidx] = cn;
            if (s == len - 1) {
                int ch = perm[d*NSEQ + rank];
                c_final[((size_t)d*NSEQ + ch)*M + m] = cn;
            }
        }
    }
}

__global__ void env_kernel(const float* __restrict__ l_states, const float* __restrict__ r_states,
                           const float* __restrict__ Wo, const float* __restrict__ Uo,
                           const float* __restrict__ bo,
                           float* __restrict__ env)
{
    __shared__ __align__(16) float l[M];
    __shared__ __align__(16) float r[M];
    const int i = blockIdx.x;
    const int tid = threadIdx.x;
    for (int m=tid; m<M; m+=blockDim.x){ l[m]=l_states[i*M+m]; r[m]=r_states[i*M+m]; }
    __syncthreads();
    for (int d=tid; d<D; d+=blockDim.x) {
        const float4* wo = reinterpret_cast<const float4*>(Wo + (size_t)d*M);
        const float4* uo = reinterpret_cast<const float4*>(Uo + (size_t)d*M);
        const float4* lv = reinterpret_cast<const float4*>(l);
        const float4* rv = reinterpret_cast<const float4*>(r);
        float acc = bo[d];
        #pragma unroll 5
        for (int q=0; q<M/4; ++q) {
            float4 a=wo[q], bv=lv[q], u=uo[q], rr=rv[q];
            acc += a.x*bv.x + a.y*bv.y + a.z*bv.z + a.w*bv.w;
            acc += u.x*rr.x + u.y*rr.y + u.z*rr.z + u.w*rr.w;
        }
        env[i*D + d] = tanhf(acc);
    }
}

__global__ void episode_kernel(const float* __restrict__ env, const int* __restrict__ target_y,
                               float* __restrict__ flags, float* __restrict__ losses)
{
    const int b = blockIdx.x;
    const int lane = threadIdx.x;
    const float* tgt = env + (size_t)(NSUP + b)*D;

    float tn = 0.f;
    for (int d=lane; d<D; d+=64){ float v=tgt[d]; tn += v*v; }
    for (int off=32; off; off>>=1) tn += __shfl_down(tn, off);
    tn = __shfl(tn, 0);

    float z[NW];
    for (int n=0; n<NW; ++n){
        const float* sup = env + (size_t)(b*NW + n)*D;
        float dot=0.f, sn=0.f;
        for (int d=lane; d<D; d+=64){ float sv=sup[d], tv=tgt[d]; dot+=sv*tv; sn+=sv*sv; }
        for (int off=32; off; off>>=1){ dot += __shfl_down(dot,off); sn += __shfl_down(sn,off); }
        dot = __shfl(dot,0); sn = __shfl(sn,0);
        float denom = fmaxf(sqrtf(sn)*sqrtf(tn), 1e-8f);
        z[n] = dot/denom*10.0f;
    }

    if (lane==0){
        float mx=z[0];
        for(int n=1;n<NW;n++) mx=fmaxf(mx,z[n]);
        float se=0.f; float p[NW];
        for(int n=0;n<NW;n++){ p[n]=expf(z[n]-mx); se+=p[n]; }
        for(int n=0;n<NW;n++) p[n]/=se;
        int am=0; float bv=p[0];
        for(int n=1;n<NW;n++) if(p[n]>bv){bv=p[n];am=n;}
        int y = target_y[b];
        flags[b] = (am==y)?1.0f:0.0f;
        float mx2=p[0]; for(int n=1;n<NW;n++) mx2=fmaxf(mx2,p[n]);
        float se2=0.f; for(int n=0;n<NW;n++) se2+=expf(p[n]-mx2);
        losses[b] = -(p[y]-mx2-logf(se2));
    }
}

__global__ void finalize_kernel(const float* __restrict__ flags, const float* __restrict__ losses,
                                float* __restrict__ out)
{
    const int lane = threadIdx.x; // 64 threads
    float f = flags[lane], l = losses[lane];
    for (int off=32; off; off>>=1){ f += __shfl_down(f,off); l += __shfl_down(l,off); }
    if (lane==0){ out[0] = f/(float)B; out[1] = l/(float)B; }
}

extern "C" void kernel_launch(void* const* d_in, const int* in_sizes, int n_in,
                              void* d_out, int out_size, void* d_ws, size_t ws_size,
                              hipStream_t stream) {
    const int*   sup_tok   = (const int*)d_in[0];
    const int*   tgt_tok   = (const int*)d_in[1];
    const int*   blank_sup = (const int*)d_in[2];
    const int*   blank_tgt = (const int*)d_in[3];
    const int*   target_y  = (const int*)d_in[4];
    const float* emb = (const float*)d_in[5];
    const float* WL  = (const float*)d_in[6];
    const float* UL  = (const float*)d_in[7];
    const float* bL  = (const float*)d_in[8];
    const float* WR  = (const float*)d_in[9];
    const float* UR  = (const float*)d_in[10];
    const float* bR  = (const float*)d_in[11];
    const float* Wo  = (const float*)d_in[12];
    const float* Uo  = (const float*)d_in[13];
    const float* bo  = (const float*)d_in[14];
    const float* c0L = (const float*)d_in[15];
    const float* c0R = (const float*)d_in[16];

    float* ws_f = (float*)d_ws;
    float* actB0   = ws_f;                              // [2*500*384]
    float* actB1   = actB0 + 2*M*NSEQ;                  // [2*500*384]
    float* c_final = actB1 + 2*M*NSEQ;                  // [2*384*500]
    float* env     = c_final + 2*NSEQ*M;                // [384*300]
    float* flags   = env + NSEQ*D;                      // [64]
    float* losses  = flags + B;                         // [64]
    int*   perm    = (int*)(losses + B);                // [2*384]
    int*   lenR    = perm + 2*NSEQ;                     // [2*384]
    int*   tmax    = lenR + 2*NSEQ;                     // [12]

    init_kernel<<<(2*M*NSEQ + 255)/256, 256, 0, stream>>>(c0L, c0R, actB0, c_final);
    sort_kernel<<<1, NSEQ, 0, stream>>>(blank_sup, blank_tgt, perm, lenR, tmax);

    for (int s = 0; s < NSTEP; ++s) {
        float* cur  = (s & 1) ? actB1 : actB0;
        float* next = (s & 1) ? actB0 : actB1;
        step_kernel<<<8*6*8, 256, 0, stream>>>(s, cur, next, c_final,
                                               WL, UL, bL, WR, UR, bR,
                                               perm, lenR, tmax, sup_tok, tgt_tok, emb);
    }

    env_kernel<<<NSEQ, 256, 0, stream>>>(c_final, c_final + NSEQ*M, Wo, Uo, bo, env);
    episode_kernel<<<B, 64, 0, stream>>>(env, target_y, flags, losses);
    finalize_kernel<<<1, 64, 0, stream>>>(flags, losses, (float*)d_out);
}

// Round 8
// 5244.450 us; speedup vs baseline: 23.1813x; 1.3657x over previous
//
#include <hip/hip_runtime.h>
#include <math.h>

#define V 13000
#define D 300
#define M 500
#define B 64
#define NW 5
#define T 128
#define NSUP (B*NW)        // 320
#define NSEQ (NSUP + B)    // 384
#define CT 32              // chains per tile
#define NCT 12             // 384/32
#define MT 16              // m per block
#define NMT 32             // m tiles (512 slots, clamp at 500)
#define KSPL 4             // K splits, one wave each
#define CHK 20             // k per chunk
#define CKS 10             // chunks per split (4*10*20 = 800 = K)
#define XCH 15             // global chunks < 15 read x (emb), else c (actB)
#define NSTEP (T-1)        // 127
#define ASZ (KSPL*CHK*MT*4)   // 5120 floats
#define BSZ (KSPL*CHK*CT)     // 2560 floats

__device__ __forceinline__ float sigmoidf_(float x){ return 1.0f/(1.0f+expf(-x)); }

// actB layout: actB[(d*M + m)*NSEQ + rank]  (k-major, rank minor -> coalesced)
// c_final layout: c_final[(d*NSEQ + chain)*M + m]

__global__ void init_kernel(const float* __restrict__ c0L, const float* __restrict__ c0R,
                            float* __restrict__ actB0, float* __restrict__ c_final)
{
    int idx = blockIdx.x*256 + threadIdx.x;      // 2*M*NSEQ
    if (idx >= 2*M*NSEQ) return;
    int d = idx / (M*NSEQ);
    int rem = idx % (M*NSEQ);
    int m = rem / NSEQ;
    int r = rem % NSEQ;
    float v = d ? c0R[m] : c0L[m];
    actB0[((size_t)d*M + m)*NSEQ + r] = v;
    c_final[((size_t)d*NSEQ + r)*M + m] = v;
}

__global__ void sort_kernel(const int* __restrict__ blank_sup, const int* __restrict__ blank_tgt,
                            int* __restrict__ perm, int* __restrict__ lenR, int* __restrict__ tmax)
{
    __shared__ int L0[NSEQ], L1[NSEQ];
    int tid = threadIdx.x;                       // 384 threads
    int blank = (tid < NSUP) ? blank_sup[tid] : blank_tgt[tid - NSUP];
    int l0 = blank, l1 = (T-1) - blank;
    L0[tid] = l0; L1[tid] = l1;
    __syncthreads();
    int r0 = 0, r1 = 0;
    for (int j = 0; j < NSEQ; ++j) {
        int c = L0[j]; r0 += (c > l0) || (c == l0 && j < tid);
        int d = L1[j]; r1 += (d > l1) || (d == l1 && j < tid);
    }
    perm[r0] = tid;        lenR[r0] = l0;
    perm[NSEQ + r1] = tid; lenR[NSEQ + r1] = l1;
    __syncthreads();
    if (tid < 2*NCT) {
        int dir = tid / NCT, t = tid % NCT;
        tmax[tid] = lenR[dir*NSEQ + t*CT];       // descending -> first rank in tile is max
    }
}

// -------- fused per-step kernel --------
// block = (ct, dir, mt): outputs 16m x 3g x 32c; 4 waves = 4 K-splits of 200;
// thread-tile = 2m x 3g x 4c (24 acc). No barriers in the chunk loop (per-wave LDS).
__global__ __launch_bounds__(256)
void step_kernel(int s,
                 const float* __restrict__ actB_cur, float* __restrict__ actB_next,
                 float* __restrict__ c_final,
                 const float* __restrict__ WL, const float* __restrict__ UL, const float* __restrict__ bL,
                 const float* __restrict__ WR, const float* __restrict__ UR, const float* __restrict__ bR,
                 const int* __restrict__ perm, const int* __restrict__ lenR, const int* __restrict__ tmax,
                 const int* __restrict__ sup_tok, const int* __restrict__ tgt_tok,
                 const float* __restrict__ emb)
{
    // bid = ct*64 + dir*32 + mt  -> blocks sharing a weight panel (dir,mt) share bid%8 (XCD)
    const int bid = blockIdx.x;                  // 768
    const int ct = bid >> 6;
    const int dm = bid & 63;
    const int d  = dm >> 5;
    const int mt = dm & 31;
    if (s >= tmax[d*NCT + ct]) return;

    __shared__ float smem[ASZ + BSZ];            // 7680 floats; reused for reduction
    __shared__ int tok_s[CT], len_s[CT];

    const int tid  = threadIdx.x;
    const int ks   = tid >> 6;                   // wave = K split
    const int lane = tid & 63;
    const int ty   = lane >> 3;                  // 0..7 (m pair)
    const int tx   = lane & 7;                   // 0..7 (chain quad)
    const int rank0 = ct*CT;

    if (tid < CT) {
        int rank = rank0 + tid;
        int ch = perm[d*NSEQ + rank];
        len_s[tid] = lenR[d*NSEQ + rank];
        int tpos = d ? (T-1-s) : s;
        tok_s[tid] = (ch < NSUP) ? sup_tok[ch*T + tpos] : tgt_tok[(ch-NSUP)*T + tpos];
    }
    __syncthreads();

    const float* Wd = d ? WR : WL;
    const float* Ud = d ? UR : UL;
    const float* bias = d ? bR : bL;

    float* As = smem;                            // [ks][kk][ml][4]: (k, m, gate)
    float* Bs = smem + ASZ;                      // [ks][kk][c]

    float acc[2][3][4];
    #pragma unroll
    for (int j=0;j<2;++j)
        #pragma unroll
        for (int g=0;g<3;++g)
            #pragma unroll
            for (int c=0;c<4;++c) acc[j][g][c] = 0.f;

    float4 aR[4];
    float4 bR4[3];

    auto loadA = [&](int gc){
        const bool isx = (gc < XCH);
        const int k0 = gc*CHK;
        #pragma unroll
        for (int i=0;i<4;++i){
            int slot = lane + 64*i;              // 240 f4: 48 rows x 5
            if (slot < 240){
                int row = slot/5, kq = slot%5;
                int g = row >> 4, ml = row & 15;
                int m = mt*MT + ml;
                float4 v = make_float4(0.f,0.f,0.f,0.f);
                if (m < M){
                    const float* src = isx ? (Wd + (size_t)(g*M + m)*D + k0 + kq*4)
                                           : (Ud + (size_t)(g*M + m)*M + (k0-300) + kq*4);
                    v = *(const float4*)src;
                }
                aR[i] = v;
            }
        }
    };
    auto loadB = [&](int gc){
        const int k0 = gc*CHK;
        if (gc < XCH){
            #pragma unroll
            for (int i=0;i<3;++i){
                int slot = lane + 64*i;          // 160 f4: 32 chains x 5
                if (slot < 160){
                    int c = slot/5, kq = slot%5;
                    bR4[i] = *(const float4*)(emb + (size_t)tok_s[c]*D + k0 + kq*4);
                }
            }
        } else {
            #pragma unroll
            for (int i=0;i<3;++i){
                int slot = lane + 64*i;          // 160 f4: 20 k x 8 quads
                if (slot < 160){
                    int kk = slot >> 3, c4 = slot & 7;
                    bR4[i] = *(const float4*)(actB_cur + ((size_t)d*M + (k0-300) + kk)*NSEQ + rank0 + c4*4);
                }
            }
        }
    };
    auto writeAB = [&](int gc){
        #pragma unroll
        for (int i=0;i<4;++i){
            int slot = lane + 64*i;
            if (slot < 240){
                int row = slot/5, kq = slot%5;
                int g = row >> 4, ml = row & 15;
                float4 v = aR[i];
                As[((ks*CHK + kq*4+0)*MT + ml)*4 + g] = v.x;
                As[((ks*CHK + kq*4+1)*MT + ml)*4 + g] = v.y;
                As[((ks*CHK + kq*4+2)*MT + ml)*4 + g] = v.z;
                As[((ks*CHK + kq*4+3)*MT + ml)*4 + g] = v.w;
            }
        }
        if (gc < XCH){
            #pragma unroll
            for (int i=0;i<3;++i){
                int slot = lane + 64*i;
                if (slot < 160){
                    int c = slot/5, kq = slot%5;
                    float4 v = bR4[i];
                    Bs[(ks*CHK + kq*4+0)*CT + c] = v.x;
                    Bs[(ks*CHK + kq*4+1)*CT + c] = v.y;
                    Bs[(ks*CHK + kq*4+2)*CT + c] = v.z;
                    Bs[(ks*CHK + kq*4+3)*CT + c] = v.w;
                }
            }
        } else {
            #pragma unroll
            for (int i=0;i<3;++i){
                int slot = lane + 64*i;
                if (slot < 160){
                    int kk = slot >> 3, c4 = slot & 7;
                    *(float4*)&Bs[(ks*CHK + kk)*CT + c4*4] = bR4[i];
                }
            }
        }
    };

#define FMA4(AC, AV, BV) AC[0] += (AV)*(BV).x; AC[1] += (AV)*(BV).y; AC[2] += (AV)*(BV).z; AC[3] += (AV)*(BV).w;

    // chunk loop: barrier-free (each wave owns its LDS region; per-wave DS ops are in-order)
    loadA(ks*CKS); loadB(ks*CKS);
    for (int ck = 0; ck < CKS; ++ck){
        const int gc = ks*CKS + ck;
        writeAB(gc);
        if (ck + 1 < CKS){ loadA(gc+1); loadB(gc+1); }
        #pragma unroll
        for (int kk = 0; kk < CHK; ++kk){
            float4 a0 = *(const float4*)&As[((ks*CHK + kk)*MT + ty*2    )*4];
            float4 a1 = *(const float4*)&As[((ks*CHK + kk)*MT + ty*2 + 1)*4];
            float4 b  = *(const float4*)&Bs[(ks*CHK + kk)*CT + tx*4];
            FMA4(acc[0][0], a0.x, b);
            FMA4(acc[0][1], a0.y, b);
            FMA4(acc[0][2], a0.z, b);
            FMA4(acc[1][0], a1.x, b);
            FMA4(acc[1][1], a1.y, b);
            FMA4(acc[1][2], a1.z, b);
        }
    }

    // ---- cross-split reduction through LDS (reuse smem) ----
    __syncthreads();
    float* red = smem;                           // [ks][ml][3][CT] = 6144 floats
    #pragma unroll
    for (int j=0;j<2;++j){
        int ml = ty*2 + j;
        #pragma unroll
        for (int g=0;g<3;++g){
            *(float4*)&red[((ks*MT + ml)*3 + g)*CT + tx*4] =
                make_float4(acc[j][g][0], acc[j][g][1], acc[j][g][2], acc[j][g][3]);
        }
    }
    __syncthreads();

    // ---- final: sum splits + bias, gates, cell update (2 cells per thread) ----
    #pragma unroll
    for (int q=0;q<2;++q){
        int cell = tid*2 + q;                    // 512 cells = 16m x 32c
        int ml = cell >> 5, c = cell & 31;
        int m = mt*MT + ml;
        if (m < M){
            float g0 = bias[m], g1 = bias[M + m], g2 = bias[2*M + m];
            #pragma unroll
            for (int kq=0;kq<KSPL;++kq){
                g0 += red[((kq*MT + ml)*3 + 0)*CT + c];
                g1 += red[((kq*MT + ml)*3 + 1)*CT + c];
                g2 += red[((kq*MT + ml)*3 + 2)*CT + c];
            }
            int rank = rank0 + c;
            int len  = len_s[c];
            size_t cidx = ((size_t)d*M + m)*NSEQ + rank;
            float cold = actB_cur[cidx];
            float f  = sigmoidf_(g0);
            float i2 = sigmoidf_(g1);
            float cb = tanhf(g2);
            float cn = (s < len) ? (f*cold + i2*cb) : cold;
            actB_next[cidx] = cn;
            if (s == len - 1){
                int ch = perm[d*NSEQ + rank];
                c_final[((size_t)d*NSEQ + ch)*M + m] = cn;
            }
        }
    }
#undef FMA4
}

__global__ void env_kernel(const float* __restrict__ l_states, const float* __restrict__ r_states,
                           const float* __restrict__ Wo, const float* __restrict__ Uo,
                           const float* __restrict__ bo,
                           float* __restrict__ env)
{
    __shared__ __align__(16) float l[M];
    __shared__ __align__(16) float r[M];
    const int i = blockIdx.x;
    const int tid = threadIdx.x;
    for (int m=tid; m<M; m+=blockDim.x){ l[m]=l_states[i*M+m]; r[m]=r_states[i*M+m]; }
    __syncthreads();
    for (int d=tid; d<D; d+=blockDim.x) {
        const float4* wo = reinterpret_cast<const float4*>(Wo + (size_t)d*M);
        const float4* uo = reinterpret_cast<const float4*>(Uo + (size_t)d*M);
        const float4* lv = reinterpret_cast<const float4*>(l);
        const float4* rv = reinterpret_cast<const float4*>(r);
        float acc = bo[d];
        #pragma unroll 5
        for (int q=0; q<M/4; ++q) {
            float4 a=wo[q], bv=lv[q], u=uo[q], rr=rv[q];
            acc += a.x*bv.x + a.y*bv.y + a.z*bv.z + a.w*bv.w;
            acc += u.x*rr.x + u.y*rr.y + u.z*rr.z + u.w*rr.w;
        }
        env[i*D + d] = tanhf(acc);
    }
}

__global__ void episode_kernel(const float* __restrict__ env, const int* __restrict__ target_y,
                               float* __restrict__ flags, float* __restrict__ losses)
{
    const int b = blockIdx.x;
    const int lane = threadIdx.x;
    const float* tgt = env + (size_t)(NSUP + b)*D;

    float tn = 0.f;
    for (int d=lane; d<D; d+=64){ float v=tgt[d]; tn += v*v; }
    for (int off=32; off; off>>=1) tn += __shfl_down(tn, off);
    tn = __shfl(tn, 0);

    float z[NW];
    for (int n=0; n<NW; ++n){
        const float* sup = env + (size_t)(b*NW + n)*D;
        float dot=0.f, sn=0.f;
        for (int d=lane; d<D; d+=64){ float sv=sup[d], tv=tgt[d]; dot+=sv*tv; sn+=sv*sv; }
        for (int off=32; off; off>>=1){ dot += __shfl_down(dot,off); sn += __shfl_down(sn,off); }
        dot = __shfl(dot,0); sn = __shfl(sn,0);
        float denom = fmaxf(sqrtf(sn)*sqrtf(tn), 1e-8f);
        z[n] = dot/denom*10.0f;
    }

    if (lane==0){
        float mx=z[0];
        for(int n=1;n<NW;n++) mx=fmaxf(mx,z[n]);
        float se=0.f; float p[NW];
        for(int n=0;n<NW;n++){ p[n]=expf(z[n]-mx); se+=p[n]; }
        for(int n=0;n<NW;n++) p[n]/=se;
        int am=0; float bv=p[0];
        for(int n=1;n<NW;n++) if(p[n]>bv){bv=p[n];am=n;}
        int y = target_y[b];
        flags[b] = (am==y)?1.0f:0.0f;
        float mx2=p[0]; for(int n=1;n<NW;n++) mx2=fmaxf(mx2,p[n]);
        float se2=0.f; for(int n=0;n<NW;n++) se2+=expf(p[n]-mx2);
        losses[b] = -(p[y]-mx2-logf(se2));
    }
}

__global__ void finalize_kernel(const float* __restrict__ flags, const float* __restrict__ losses,
                                float* __restrict__ out)
{
    const int lane = threadIdx.x; // 64 threads
    float f = flags[lane], l = losses[lane];
    for (int off=32; off; off>>=1){ f += __shfl_down(f,off); l += __shfl_down(l,off); }
    if (lane==0){ out[0] = f/(float)B; out[1] = l/(float)B; }
}

extern "C" void kernel_launch(void* const* d_in, const int* in_sizes, int n_in,
                              void* d_out, int out_size, void* d_ws, size_t ws_size,
                              hipStream_t stream) {
    const int*   sup_tok   = (const int*)d_in[0];
    const int*   tgt_tok   = (const int*)d_in[1];
    const int*   blank_sup = (const int*)d_in[2];
    const int*   blank_tgt = (const int*)d_in[3];
    const int*   target_y  = (const int*)d_in[4];
    const float* emb = (const float*)d_in[5];
    const float* WL  = (const float*)d_in[6];
    const float* UL  = (const float*)d_in[7];
    const float* bL  = (const float*)d_in[8];
    const float* WR  = (const float*)d_in[9];
    const float* UR  = (const float*)d_in[10];
    const float* bR  = (const float*)d_in[11];
    const float* Wo  = (const float*)d_in[12];
    const float* Uo  = (const float*)d_in[13];
    const float* bo  = (const float*)d_in[14];
    const float* c0L = (const float*)d_in[15];
    const float* c0R = (const float*)d_in[16];

    float* ws_f = (float*)d_ws;
    float* actB0   = ws_f;                              // [2*500*384]
    float* actB1   = actB0 + 2*M*NSEQ;                  // [2*500*384]
    float* c_final = actB1 + 2*M*NSEQ;                  // [2*384*500]
    float* env     = c_final + 2*NSEQ*M;                // [384*300]
    float* flags   = env + NSEQ*D;                      // [64]
    float* losses  = flags + B;                         // [64]
    int*   perm    = (int*)(losses + B);                // [2*384]
    int*   lenR    = perm + 2*NSEQ;                     // [2*384]
    int*   tmax    = lenR + 2*NSEQ;                     // [24]

    init_kernel<<<(2*M*NSEQ + 255)/256, 256, 0, stream>>>(c0L, c0R, actB0, c_final);
    sort_kernel<<<1, NSEQ, 0, stream>>>(blank_sup, blank_tgt, perm, lenR, tmax);

    for (int s = 0; s < NSTEP; ++s) {
        float* cur  = (s & 1) ? actB1 : actB0;
        float* next = (s & 1) ? actB0 : actB1;
        step_kernel<<<NCT*64, 256, 0, stream>>>(s, cur, next, c_final,
                                                WL, UL, bL, WR, UR, bR,
                                                perm, lenR, tmax, sup_tok, tgt_tok, emb);
    }

    env_kernel<<<NSEQ, 256, 0, stream>>>(c_final, c_final + NSEQ*M, Wo, Uo, bo, env);
    episode_kernel<<<B, 64, 0, stream>>>(env, target_y, flags, losses);
    finalize_kernel<<<1, 64, 0, stream>>>(flags, losses, (float*)d_out);
}